// Round 18
// baseline (625.299 us; speedup 1.0000x reference)
//
#include <hip/hip_runtime.h>

// Problem constants (from reference)
#define NN 100000      // nodes
#define NE 1600000     // edges
#define NBATCH 100     // graphs
#define NBUCK 391      // ceil(NN / 256) coarse buckets for CSR build
constexpr float EPS = 1e-5f;

typedef unsigned short ushort_t;
typedef unsigned int uint_t;
typedef unsigned char uchar_t;

using short8 = __attribute__((ext_vector_type(8))) short;   // 8 bf16 (4 VGPRs)
using floatx4 = __attribute__((ext_vector_type(4))) float;  // 4 fp32 acc
using floatx2 = __attribute__((ext_vector_type(2))) float;

__device__ __forceinline__ float lrelu(float x) { return x > 0.f ? x : 0.01f * x; }

__device__ __forceinline__ float b2f(ushort_t u) {
    union { uint_t i; float f; } c; c.i = ((uint_t)u) << 16; return c.f;
}
__device__ __forceinline__ ushort_t f2b(float f) {
    union { float f; uint_t i; } c; c.f = f;
    uint_t u = c.i;
    return (ushort_t)((u + 0x7FFFu + ((u >> 16) & 1u)) >> 16);   // RNE
}
__device__ __forceinline__ void unpack8(const uint4 u, float* f) {
    f[0] = b2f(u.x & 0xffff); f[1] = b2f(u.x >> 16);
    f[2] = b2f(u.y & 0xffff); f[3] = b2f(u.y >> 16);
    f[4] = b2f(u.z & 0xffff); f[5] = b2f(u.z >> 16);
    f[6] = b2f(u.w & 0xffff); f[7] = b2f(u.w >> 16);
}
__device__ __forceinline__ void unpack8_f8(const uint2 u, float* f) {
    floatx2 a = __builtin_amdgcn_cvt_pk_f32_fp8(u.x, false);
    floatx2 b = __builtin_amdgcn_cvt_pk_f32_fp8(u.x, true);
    floatx2 c = __builtin_amdgcn_cvt_pk_f32_fp8(u.y, false);
    floatx2 d = __builtin_amdgcn_cvt_pk_f32_fp8(u.y, true);
    f[0] = a[0]; f[1] = a[1]; f[2] = b[0]; f[3] = b[1];
    f[4] = c[0]; f[5] = c[1]; f[6] = d[0]; f[7] = d[1];
}

// ---------------- bucketed CSR build ----------------

__global__ __launch_bounds__(256) void k_bcount(const int* __restrict__ dst,
                                                int* __restrict__ bcnt) {
    __shared__ int h[NBUCK];
    for (int i = threadIdx.x; i < NBUCK; i += 256) h[i] = 0;
    __syncthreads();
    for (int e = blockIdx.x * 256 + threadIdx.x; e < NE; e += gridDim.x * 256)
        atomicAdd(&h[dst[e] >> 8], 1);
    __syncthreads();
    for (int i = threadIdx.x; i < NBUCK; i += 256)
        if (h[i]) atomicAdd(&bcnt[i], h[i]);
}

// scan bucket totals + batch boundaries (batch sorted), 1 block
__global__ __launch_bounds__(512) void k_bscan(const int* __restrict__ bcnt,
                                               int* __restrict__ bbase,
                                               int* __restrict__ bcur,
                                               int* __restrict__ rowstart,
                                               const int* __restrict__ batch,
                                               int* __restrict__ bstart) {
    __shared__ int s[512];
    const int t = threadIdx.x;
    const int v = (t < NBUCK) ? bcnt[t] : 0;
    s[t] = v;
    __syncthreads();
    for (int off = 1; off < 512; off <<= 1) {
        int o = (t >= off) ? s[t - off] : 0;
        __syncthreads();
        s[t] += o;
        __syncthreads();
    }
    const int excl = s[t] - v;
    if (t < NBUCK) { bbase[t] = excl; bcur[t] = excl; }
    if (t == 0) { bbase[NBUCK] = NE; rowstart[NN] = NE; }
    if (t <= NBATCH) {
        int lo = 0, hi = NN;
        while (lo < hi) {
            int mid = (lo + hi) >> 1;
            if (batch[mid] < t) lo = mid + 1; else hi = mid;
        }
        bstart[t] = lo;
    }
}

__global__ __launch_bounds__(256) void k_bscatter(const int* __restrict__ dst,
                                                  const int* __restrict__ srcv,
                                                  const float* __restrict__ ew,
                                                  int* __restrict__ bcur,
                                                  int2* __restrict__ ebuf) {
    __shared__ int h[NBUCK];
    __shared__ int lcur[NBUCK];
    const int chunk = (NE + gridDim.x - 1) / gridDim.x;
    const int beg = blockIdx.x * chunk;
    const int end = (beg + chunk < NE) ? beg + chunk : NE;
    for (int i = threadIdx.x; i < NBUCK; i += 256) h[i] = 0;
    __syncthreads();
    for (int e = beg + threadIdx.x; e < end; e += 256)
        atomicAdd(&h[dst[e] >> 8], 1);
    __syncthreads();
    for (int i = threadIdx.x; i < NBUCK; i += 256)
        lcur[i] = h[i] ? atomicAdd(&bcur[i], h[i]) : 0;
    __syncthreads();
    for (int e = beg + threadIdx.x; e < end; e += 256) {
        const int d = dst[e];
        const int pos = atomicAdd(&lcur[d >> 8], 1);
        ebuf[pos] = make_int2(srcv[e] | ((d & 255) << 20), __float_as_int(ew[e]));
    }
}

__global__ __launch_bounds__(256) void k_bfinal(const int2* __restrict__ ebuf,
                                                const int* __restrict__ bbase,
                                                int* __restrict__ rowstart,
                                                int2* __restrict__ csr_pair) {
    __shared__ int h[256];
    __shared__ int cur[256];
    const int b = blockIdx.x;
    const int t = threadIdx.x;
    const int base = bbase[b];
    const int cnt = bbase[b + 1] - base;
    h[t] = 0;
    __syncthreads();
    for (int i = t; i < cnt; i += 256)
        atomicAdd(&h[(ebuf[base + i].x >> 20) & 255], 1);
    __syncthreads();
    const int v = h[t];
    cur[t] = v;
    __syncthreads();
    for (int off = 1; off < 256; off <<= 1) {
        int o = (t >= off) ? cur[t - off] : 0;
        __syncthreads();
        cur[t] += o;
        __syncthreads();
    }
    const int excl = cur[t] - v;
    const int n = (b << 8) + t;
    if (n < NN) rowstart[n] = base + excl;
    __syncthreads();
    cur[t] = excl;
    __syncthreads();
    for (int i = t; i < cnt; i += 256) {
        const int2 p = ebuf[base + i];
        const int loc = (p.x >> 20) & 255;
        const int pos = base + atomicAdd(&cur[loc], 1);
        csr_pair[pos] = make_int2(p.x & 0xFFFFF, p.y);
    }
}

// ---------------- weight pack: fragment-major, all three convs in one launch -----------------

__device__ __forceinline__ void packone(int idx, const float* __restrict__ wrel,
                                        const float* __restrict__ wroot,
                                        ushort_t* __restrict__ wf, int K, int K2, int DOUT) {
    const int col = idx / K2, k = idx - col * K2;
    const float v = (k < K) ? wrel[k * DOUT + col] : wroot[(k - K) * DOUT + col];
    const int ct = col >> 4, m = col & 15;
    const int kb = k >> 5, q = (k >> 3) & 3, j = k & 7;
    const int lane = m + (q << 4);
    wf[(((size_t)(ct * (K2 / 32) + kb) * 64 + lane) << 3) + j] = f2b(v);
}

__global__ void k_wpackall(const float* __restrict__ wr1, const float* __restrict__ wo1,
                           const float* __restrict__ wr2, const float* __restrict__ wo2,
                           const float* __restrict__ wr3, const float* __restrict__ wo3,
                           ushort_t* __restrict__ w1T, ushort_t* __restrict__ w2T,
                           ushort_t* __restrict__ w3T) {
    int idx = blockIdx.x * 256 + threadIdx.x;
    if (idx < 2048)              packone(idx, wr1, wo1, w1T, 16, 32, 64);
    else if (idx < 18432)        packone(idx - 2048, wr2, wo2, w2T, 64, 128, 128);
    else if (idx < 83968)        packone(idx - 18432, wr3, wo3, w3T, 128, 256, 256);
}

// ---------------- embedding gather -> bf16 x-half of xcat0 ----------------------------------

__global__ void k_gather_b(const int* __restrict__ xi, const float* __restrict__ emb,
                           ushort_t* __restrict__ xcat0) {
    int n = blockIdx.x * blockDim.x + threadIdx.x;
    if (n >= NN) return;
    const float* e = emb + ((size_t)xi[n] << 4);
    uint_t u[8];
#pragma unroll
    for (int j = 0; j < 8; ++j)
        u[j] = (uint_t)f2b(e[2 * j]) | ((uint_t)f2b(e[2 * j + 1]) << 16);
    uint4* o = (uint4*)(xcat0 + (size_t)n * 32 + 16);
    o[0] = {u[0], u[1], u[2], u[3]};
    o[1] = {u[4], u[5], u[6], u[7]};
}

// ---------------- aggregate (bf16 in/out) for conv1/conv2 -----------------------------------

template <int D>
__global__ void k_aggregate_b(ushort_t* __restrict__ xcat, const int2* __restrict__ csr_pair,
                              const int* __restrict__ rowstart) {
    constexpr int LPN = D / 8;
    constexpr int EP = 64 / LPN;
    const int n = blockIdx.x * 4 + (threadIdx.x >> 6);
    const int lane = threadIdx.x & 63;
    const int sl = lane % LPN;
    const int eg = lane / LPN;
    if (n >= NN) return;
    const int beg = rowstart[n], end = rowstart[n + 1];
    float a0[8] = {}, a1[8] = {};
    int i = beg + eg;
    for (; i + EP < end; i += 2 * EP) {
        const int2 p0 = csr_pair[i];
        const int2 p1 = csr_pair[i + EP];
        const float w0 = __int_as_float(p0.y);
        const float w1 = __int_as_float(p1.y);
        const uint4 u0 = *(const uint4*)(xcat + (size_t)p0.x * (2 * D) + D + sl * 8);
        const uint4 u1 = *(const uint4*)(xcat + (size_t)p1.x * (2 * D) + D + sl * 8);
        float f0[8], f1[8];
        unpack8(u0, f0); unpack8(u1, f1);
#pragma unroll
        for (int j = 0; j < 8; ++j) { a0[j] += f0[j] * w0; a1[j] += f1[j] * w1; }
    }
    if (i < end) {
        const int2 p0 = csr_pair[i];
        const float w0 = __int_as_float(p0.y);
        const uint4 u0 = *(const uint4*)(xcat + (size_t)p0.x * (2 * D) + D + sl * 8);
        float f0[8];
        unpack8(u0, f0);
#pragma unroll
        for (int j = 0; j < 8; ++j) a0[j] += f0[j] * w0;
    }
#pragma unroll
    for (int j = 0; j < 8; ++j) a0[j] += a1[j];
#pragma unroll
    for (int m = LPN; m < 64; m <<= 1)
#pragma unroll
        for (int j = 0; j < 8; ++j) a0[j] += __shfl_xor(a0[j], m);
    if (eg == 0) {
        uint_t u[4];
#pragma unroll
        for (int j = 0; j < 4; ++j)
            u[j] = (uint_t)f2b(a0[2 * j]) | ((uint_t)f2b(a0[2 * j + 1]) << 16);
        *(uint4*)(xcat + (size_t)n * (2 * D) + sl * 8) = {u[0], u[1], u[2], u[3]};
    }
}

// ---------------- aggregate for conv3: fp8 x2 reads, 4x edge unroll -------------------------

__global__ void k_aggregate_f8(ushort_t* __restrict__ xcat, const uchar_t* __restrict__ x8,
                               const int2* __restrict__ csr_pair, const int* __restrict__ rowstart) {
    constexpr int D = 128;
    constexpr int LPN = 16;
    constexpr int EP = 4;
    const int n = blockIdx.x * 4 + (threadIdx.x >> 6);
    const int lane = threadIdx.x & 63;
    const int sl = lane % LPN;
    const int eg = lane / LPN;
    if (n >= NN) return;
    const int beg = rowstart[n], end = rowstart[n + 1];
    float a0[8] = {}, a1[8] = {}, a2[8] = {}, a3[8] = {};
    int i = beg + eg;
    for (; i + 3 * EP < end; i += 4 * EP) {
        const int2 p0 = csr_pair[i];
        const int2 p1 = csr_pair[i + EP];
        const int2 p2 = csr_pair[i + 2 * EP];
        const int2 p3 = csr_pair[i + 3 * EP];
        const uint2 u0 = *(const uint2*)(x8 + (size_t)p0.x * D + sl * 8);
        const uint2 u1 = *(const uint2*)(x8 + (size_t)p1.x * D + sl * 8);
        const uint2 u2 = *(const uint2*)(x8 + (size_t)p2.x * D + sl * 8);
        const uint2 u3 = *(const uint2*)(x8 + (size_t)p3.x * D + sl * 8);
        const float w0 = __int_as_float(p0.y);
        const float w1 = __int_as_float(p1.y);
        const float w2 = __int_as_float(p2.y);
        const float w3 = __int_as_float(p3.y);
        float f0[8], f1[8], f2[8], f3[8];
        unpack8_f8(u0, f0); unpack8_f8(u1, f1); unpack8_f8(u2, f2); unpack8_f8(u3, f3);
#pragma unroll
        for (int j = 0; j < 8; ++j) {
            a0[j] += f0[j] * w0; a1[j] += f1[j] * w1;
            a2[j] += f2[j] * w2; a3[j] += f3[j] * w3;
        }
    }
    for (; i < end; i += EP) {
        const int2 p0 = csr_pair[i];
        const float w0 = __int_as_float(p0.y);
        const uint2 u0 = *(const uint2*)(x8 + (size_t)p0.x * D + sl * 8);
        float f0[8];
        unpack8_f8(u0, f0);
#pragma unroll
        for (int j = 0; j < 8; ++j) a0[j] += f0[j] * w0;
    }
#pragma unroll
    for (int j = 0; j < 8; ++j) a0[j] += (a1[j] + a2[j]) + a3[j];
#pragma unroll
    for (int m = LPN; m < 64; m <<= 1)
#pragma unroll
        for (int j = 0; j < 8; ++j) a0[j] += __shfl_xor(a0[j], m);
    if (eg == 0) {
        uint_t u[4];
#pragma unroll
        for (int j = 0; j < 4; ++j)
            u[j] = (uint_t)f2b(a0[2 * j]) | ((uint_t)f2b(a0[2 * j + 1]) << 16);
        *(uint4*)(xcat + (size_t)n * (2 * D) + sl * 8) = {u[0], u[1], u[2], u[3]};
    }
}

// ---------------- conv GEMM via bf16 MFMA (fragment-major B) --------------------------------
// MODE 1: fp32 out + per-(batch,col) sum/sumsq stats. MODE 2: gf fusion (split-K via blockIdx.y).

template <int K2, int DOUT, int MODE, int NSPLIT>
__global__ __launch_bounds__(256) void k_conv_mfma(
        const ushort_t* __restrict__ xcat, const ushort_t* __restrict__ wfrag,
        const float* __restrict__ brel, float* __restrict__ outp,
        const int* __restrict__ batch, const int* __restrict__ bstart,
        float* __restrict__ sacc, float* __restrict__ qacc) {
    constexpr int CW = DOUT / 64;
    constexpr int KBTOT = K2 / 32;
    constexpr int KSTEPS = KBTOT / NSPLIT;
    const int lane = threadIdx.x & 63;
    const int wv = threadIdx.x >> 6;
    const int m = lane & 15;
    const int quad = lane >> 4;
    const int r0 = blockIdx.x * 64;
    const int kb0 = blockIdx.y * KSTEPS;

    floatx4 acc[4][CW] = {};

    const ushort_t* arow[4];
#pragma unroll
    for (int r = 0; r < 4; ++r) {
        int an = r0 + r * 16 + m; if (an >= NN) an = NN - 1;
        arow[r] = xcat + (size_t)an * K2 + quad * 8 + kb0 * 32;
    }
    const ushort_t* bfr[CW];
#pragma unroll
    for (int c = 0; c < CW; ++c)
        bfr[c] = wfrag + (((size_t)((wv * CW + c) * KBTOT + kb0) * 64 + lane) << 3);

#pragma unroll
    for (int s = 0; s < KSTEPS; ++s) {
        short8 a[4], b[CW];
#pragma unroll
        for (int r = 0; r < 4; ++r) a[r] = *(const short8*)(arow[r] + s * 32);
#pragma unroll
        for (int c = 0; c < CW; ++c) b[c] = *(const short8*)(bfr[c] + (size_t)s * 512);
#pragma unroll
        for (int r = 0; r < 4; ++r)
#pragma unroll
            for (int c = 0; c < CW; ++c)
                acc[r][c] = __builtin_amdgcn_mfma_f32_16x16x32_bf16(a[r], b[c], acc[r][c], 0, 0, 0);
    }

    float bias[CW];
#pragma unroll
    for (int c = 0; c < CW; ++c)
        bias[c] = (NSPLIT == 1 || blockIdx.y == 0) ? brel[(wv * CW + c) * 16 + m] : 0.f;

    if constexpr (MODE == 1) {
#pragma unroll
        for (int c = 0; c < CW; ++c) {
            const int col = (wv * CW + c) * 16 + m;
#pragma unroll
            for (int r = 0; r < 4; ++r)
#pragma unroll
                for (int rr = 0; rr < 4; ++rr) {
                    const int row = r0 + r * 16 + quad * 4 + rr;
                    if (row < NN)
                        outp[(size_t)row * DOUT + col] = acc[r][c][rr] + bias[c];
                }
        }
        const int rtop = (r0 + 63 < NN) ? r0 + 63 : NN - 1;
        const int sb0 = batch[r0];
        const int sb1 = batch[rtop];
        for (int sb = sb0; sb <= sb1; ++sb) {
            const int lo = (bstart[sb] > r0) ? bstart[sb] : r0;
            int hi = bstart[sb + 1];
            if (hi > r0 + 64) hi = r0 + 64;
            float s[CW], q[CW];
#pragma unroll
            for (int c = 0; c < CW; ++c) { s[c] = 0.f; q[c] = 0.f; }
#pragma unroll
            for (int r = 0; r < 4; ++r)
#pragma unroll
                for (int rr = 0; rr < 4; ++rr) {
                    const int row = r0 + r * 16 + quad * 4 + rr;
                    if (row >= lo && row < hi) {
#pragma unroll
                        for (int c = 0; c < CW; ++c) {
                            const float v = acc[r][c][rr] + bias[c];
                            s[c] += v; q[c] += v * v;
                        }
                    }
                }
#pragma unroll
            for (int c = 0; c < CW; ++c) {
                s[c] += __shfl_xor(s[c], 16); s[c] += __shfl_xor(s[c], 32);
                q[c] += __shfl_xor(q[c], 16); q[c] += __shfl_xor(q[c], 32);
            }
            if (quad == 0) {
#pragma unroll
                for (int c = 0; c < CW; ++c) {
                    const int col = (wv * CW + c) * 16 + m;
                    atomicAdd(&sacc[sb * DOUT + col], s[c]);
                    atomicAdd(&qacc[sb * DOUT + col], q[c]);
                }
            }
        }
    } else {
        const int rtop = (r0 + 63 < NN) ? r0 + 63 : NN - 1;
        const int sb0 = batch[r0];
        const int sb1 = batch[rtop];
        for (int sb = sb0; sb <= sb1; ++sb) {
            const int lo = (bstart[sb] > r0) ? bstart[sb] : r0;
            int hi = bstart[sb + 1];
            if (hi > r0 + 64) hi = r0 + 64;
            float s[CW];
#pragma unroll
            for (int c = 0; c < CW; ++c) s[c] = 0.f;
#pragma unroll
            for (int r = 0; r < 4; ++r)
#pragma unroll
                for (int rr = 0; rr < 4; ++rr) {
                    const int row = r0 + r * 16 + quad * 4 + rr;
                    if (row >= lo && row < hi) {
#pragma unroll
                        for (int c = 0; c < CW; ++c) s[c] += acc[r][c][rr] + bias[c];
                    }
                }
#pragma unroll
            for (int c = 0; c < CW; ++c) {
                s[c] += __shfl_xor(s[c], 16);
                s[c] += __shfl_xor(s[c], 32);
            }
            if (quad == 0) {
#pragma unroll
                for (int c = 0; c < CW; ++c)
                    atomicAdd(&sacc[sb * 256 + (wv * CW + c) * 16 + m], s[c]);
            }
        }
    }
}

// graph features + demographics -> h0 (fused)
__global__ void k_headpre(const float* __restrict__ gfacc, const int* __restrict__ bstart,
                          const float* __restrict__ dg, const float* __restrict__ dw,
                          const float* __restrict__ db, float* __restrict__ h0) {
    int idx = blockIdx.x * blockDim.x + threadIdx.x;
    if (idx >= NBATCH * 272) return;
    int b = idx / 272, c = idx - b * 272;
    if (c < 256) {
        float cnt = fmaxf((float)(bstart[b + 1] - bstart[b]), 1.f);
        h0[idx] = gfacc[b * 256 + c] / cnt;
    } else {
        int j = c - 256;
        float acc = db[j];
        for (int k = 0; k < 4; ++k) acc += dg[b * 4 + k] * dw[k * 16 + j];
        h0[idx] = acc;
    }
}

// ---------------- graph-norm apply (1 pass) --------------------------------------------------

template <int D, int OST, bool F8>
__global__ __launch_bounds__(256) void k_gnapply(
        const float* __restrict__ xf, ushort_t* __restrict__ xout, uchar_t* __restrict__ x8out,
        const int* __restrict__ bstart, const float* __restrict__ sacc,
        const float* __restrict__ qacc, const float* __restrict__ a,
        const float* __restrict__ g, const float* __restrict__ bb) {
    const int b = blockIdx.x;
    const int col0 = blockIdx.y * 64;
    const int c4 = (threadIdx.x & 15) * 4;
    const int rg = threadIdx.x >> 4;
    const int beg = bstart[b], end = bstart[b + 1];
    const float cntf = fmaxf((float)(end - beg), 1.f);

    const float4 S = *(const float4*)&sacc[b * D + col0 + c4];
    const float4 Q = *(const float4*)&qacc[b * D + col0 + c4];
    const float4 al4 = *(const float4*)&a[col0 + c4];
    const float4 g4 = *(const float4*)&g[col0 + c4];
    const float4 bb4 = *(const float4*)&bb[col0 + c4];
    float mean[4], inv[4];
    const float Sv[4] = {S.x, S.y, S.z, S.w};
    const float Qv[4] = {Q.x, Q.y, Q.z, Q.w};
    const float av[4] = {al4.x, al4.y, al4.z, al4.w};
#pragma unroll
    for (int c = 0; c < 4; ++c) {
        const float mm = Sv[c] / cntf;
        const float ex2 = Qv[c] / cntf;
        const float var = fmaxf(ex2 - mm * mm * (2.f * av[c] - av[c] * av[c]), 0.f);
        mean[c] = mm;
        inv[c] = 1.f / sqrtf(var + EPS);
    }
    for (int r = beg + rg; r < end; r += 16) {
        const float4 v = *(const float4*)&xf[(size_t)r * D + col0 + c4];
        const float y0 = lrelu(g4.x * (v.x - av[0] * mean[0]) * inv[0] + bb4.x);
        const float y1 = lrelu(g4.y * (v.y - av[1] * mean[1]) * inv[1] + bb4.y);
        const float y2 = lrelu(g4.z * (v.z - av[2] * mean[2]) * inv[2] + bb4.z);
        const float y3 = lrelu(g4.w * (v.w - av[3] * mean[3]) * inv[3] + bb4.w);
        uint2 o;
        o.x = (uint_t)f2b(y0) | ((uint_t)f2b(y1) << 16);
        o.y = (uint_t)f2b(y2) | ((uint_t)f2b(y3) << 16);
        *(uint2*)&xout[(size_t)r * OST + col0 + c4] = o;
        if constexpr (F8) {
            uint_t p = __builtin_amdgcn_cvt_pk_fp8_f32(y0, y1, 0, false);
            p = __builtin_amdgcn_cvt_pk_fp8_f32(y2, y3, p, true);
            *(uint_t*)&x8out[(size_t)r * D + col0 + c4] = p;
        }
    }
}

// ---------------- head ----------------------------------------------------------------------

template <int K, int C>
__global__ __launch_bounds__(C) void k_head_lin(const float* __restrict__ in,
                                                const float* __restrict__ w,
                                                const float* __restrict__ bias,
                                                float* __restrict__ z, int rows) {
    __shared__ float s_in[16][K];
    const int j = threadIdx.x;
    const int r0 = blockIdx.x * 16;
    for (int idx = threadIdx.x; idx < 16 * K; idx += C) {
        int r = idx / K, k = idx - r * K;
        s_in[r][k] = (r0 + r < rows) ? in[(size_t)(r0 + r) * K + k] : 0.f;
    }
    __syncthreads();
    float acc[16];
#pragma unroll
    for (int r = 0; r < 16; ++r) acc[r] = 0.f;
    for (int k = 0; k < K; ++k) {
        const float wv = w[k * C + j];
#pragma unroll
        for (int r = 0; r < 16; ++r) acc[r] += s_in[r][k] * wv;
    }
    const float bj = bias[j];
#pragma unroll
    for (int r = 0; r < 16; ++r)
        if (r0 + r < rows) z[(size_t)(r0 + r) * C + j] = acc[r] + bj;
}

__global__ void k_head_bn(float* __restrict__ z, const float* __restrict__ g,
                          const float* __restrict__ b, int rows, int C) {
    const int j = threadIdx.x;
    if (j >= C) return;
    float s = 0.f, q = 0.f;
    for (int i = 0; i < rows; ++i) { const float v = z[i * C + j]; s += v; q += v * v; }
    const float m = s / rows;
    const float var = fmaxf(q / rows - m * m, 0.f);
    const float inv = 1.f / sqrtf(var + EPS);
    const float gg = g[j], bb = b[j];
    for (int i = 0; i < rows; ++i)
        z[i * C + j] = lrelu(gg * (z[i * C + j] - m) * inv + bb);
}

__global__ __launch_bounds__(256) void k_head_out(const float* __restrict__ h2,
                                                  const float* __restrict__ w,
                                                  const float* __restrict__ b,
                                                  float* __restrict__ out) {
    __shared__ float s[NBATCH * 65];
    for (int idx = threadIdx.x; idx < NBATCH * 64; idx += 256) {
        int i = idx >> 6, k = idx & 63;
        s[i * 65 + k] = h2[idx];
    }
    __syncthreads();
    const int i = threadIdx.x;
    if (i < NBATCH) {
        float a0 = b[0], a1 = b[1], a2 = b[2];
        for (int k = 0; k < 64; ++k) {
            const float v = s[i * 65 + k];
            a0 += v * w[k * 3 + 0];
            a1 += v * w[k * 3 + 1];
            a2 += v * w[k * 3 + 2];
        }
        out[i * 3 + 0] = a0; out[i * 3 + 1] = a1; out[i * 3 + 2] = a2;
    }
}

// ---------------- launcher ----------------

extern "C" void kernel_launch(void* const* d_in, const int* in_sizes, int n_in,
                              void* d_out, int out_size, void* d_ws, size_t ws_size,
                              hipStream_t stream) {
    const int*   x_idx  = (const int*)d_in[0];
    const int*   ei     = (const int*)d_in[1];
    const float* eattr  = (const float*)d_in[2];
    const int*   batch  = (const int*)d_in[3];
    const float* demog  = (const float*)d_in[4];
    const float* emb    = (const float*)d_in[5];
    const float* wrel1  = (const float*)d_in[6];
    const float* brel1  = (const float*)d_in[7];
    const float* wroot1 = (const float*)d_in[8];
    const float* wrel2  = (const float*)d_in[9];
    const float* brel2  = (const float*)d_in[10];
    const float* wroot2 = (const float*)d_in[11];
    const float* wrel3  = (const float*)d_in[12];
    const float* brel3  = (const float*)d_in[13];
    const float* wroot3 = (const float*)d_in[14];
    const float* gn1g = (const float*)d_in[15];
    const float* gn1b = (const float*)d_in[16];
    const float* gn1a = (const float*)d_in[17];
    const float* gn2g = (const float*)d_in[18];
    const float* gn2b = (const float*)d_in[19];
    const float* gn2a = (const float*)d_in[20];
    const float* dw   = (const float*)d_in[21];
    const float* db   = (const float*)d_in[22];
    const float* l1w  = (const float*)d_in[23];
    const float* l1b  = (const float*)d_in[24];
    const float* bn1g = (const float*)d_in[25];
    const float* bn1b = (const float*)d_in[26];
    const float* l2w  = (const float*)d_in[27];
    const float* l2b  = (const float*)d_in[28];
    const float* bn2g = (const float*)d_in[29];
    const float* bn2b = (const float*)d_in[30];
    const float* l3w  = (const float*)d_in[31];
    const float* l3b  = (const float*)d_in[32];
    float* out = (float*)d_out;

    float*    W     = (float*)d_ws;
    float*    xf    = W;                                   // fp32 conv out, 12.8M floats
    int2*     ebuf  = (int2*)W;                            // NE int2 (CSR build only)
    // contiguous zero-init region: gfacc | sacc1 | qacc1 | sacc2 | qacc2 | bcnt
    float*    gfacc = W + 12800000;                        // 25600
    float*    sacc1 = gfacc + 25600;                       // 6400
    float*    qacc1 = sacc1 + 6400;                        // 6400
    float*    sacc2 = qacc1 + 6400;                        // 12800
    float*    qacc2 = sacc2 + 12800;                       // 12800
    int*      bcnt  = (int*)(qacc2 + 12800);               // NBUCK
    ushort_t* xcat0 = (ushort_t*)(W + 25600000);           // NN*32 bf16  [agg0|x0]
    ushort_t* xcat1 = (ushort_t*)(W + 27200000);           // NN*128 bf16 [agg1|x1]
    ushort_t* xcat2 = (ushort_t*)(W + 33600000);           // NN*256 bf16 [agg2|x2]
    ushort_t* w1T   = (ushort_t*)(W + 46400000);           // 2048
    ushort_t* w2T   = w1T + 2048;                          // 16384
    ushort_t* w3T   = w2T + 16384;                         // 65536
    int2*     csr_pair = (int2*)(W + 46450000);            // NE int2
    int*      rowstart = (int*)(W + 49650000);             // NN+1
    int*      bstart   = (int*)(W + 49760000);             // NBATCH+1
    int*      bbase    = (int*)(W + 49762000);             // NBUCK+1
    int*      bcur     = (int*)(W + 49763000);             // NBUCK
    float*    h0 = W + 49770000;                           // 100*272
    float*    h1 = h0 + 27200;
    float*    h2 = h1 + 12800;
    uchar_t*  x8 = (uchar_t*)(W + 49860000);               // NN*128 fp8 e4m3 (x2 copy)

    const int* src = ei;
    const int* dst = ei + NE;

    const int mfma_blk = (NN + 63) / 64;     // 1563 (64 rows/block)
    const int nagg_blk = (NN + 3) / 4;       // 1 node/wave, 4 waves/block

    // single memset for all accumulators + bcnt (contiguous)
    hipMemsetAsync(gfacc, 0, (25600 + 6400 + 6400 + 12800 + 12800) * sizeof(float)
                             + NBUCK * sizeof(int), stream);

    // ---- bucketed CSR build (by dst) + batch bounds ----
    k_bcount<<<256, 256, 0, stream>>>(dst, bcnt);
    k_bscan<<<1, 512, 0, stream>>>(bcnt, bbase, bcur, rowstart, batch, bstart);
    k_bscatter<<<256, 256, 0, stream>>>(dst, src, eattr, bcur, ebuf);
    k_bfinal<<<NBUCK, 256, 0, stream>>>(ebuf, bbase, rowstart, csr_pair);

    k_wpackall<<<(83968 + 255) / 256, 256, 0, stream>>>(wrel1, wroot1, wrel2, wroot2,
                                                        wrel3, wroot3, w1T, w2T, w3T);

    // x0 (bf16) into xcat0 x-half
    k_gather_b<<<(NN + 255) / 256, 256, 0, stream>>>(x_idx, emb, xcat0);

    // conv1: [agg0|x0](K2=32) @ w1T -> xf (fp32 NN x 64) + graphnorm stats
    k_aggregate_b<16><<<nagg_blk, 256, 0, stream>>>(xcat0, csr_pair, rowstart);
    k_conv_mfma<32, 64, 1, 1><<<mfma_blk, 256, 0, stream>>>(xcat0, w1T, brel1, xf, batch, bstart, sacc1, qacc1);
    k_gnapply<64, 128, false><<<dim3(NBATCH, 1), 256, 0, stream>>>(xf, xcat1 + 64, nullptr,
                                                                   bstart, sacc1, qacc1, gn1a, gn1g, gn1b);

    // conv2: [agg1|x1](K2=128) @ w2T -> xf (fp32 NN x 128) + stats; apply writes bf16 + fp8
    k_aggregate_b<64><<<nagg_blk, 256, 0, stream>>>(xcat1, csr_pair, rowstart);
    k_conv_mfma<128, 128, 1, 1><<<mfma_blk, 256, 0, stream>>>(xcat1, w2T, brel2, xf, batch, bstart, sacc2, qacc2);
    k_gnapply<128, 256, true><<<dim3(NBATCH, 2), 256, 0, stream>>>(xf, xcat2 + 128, x8,
                                                                   bstart, sacc2, qacc2, gn2a, gn2g, gn2b);

    // conv3: [agg2|x2](K2=256) @ w3T -> gfacc (split-K=2, x3 never materialized)
    k_aggregate_f8<<<nagg_blk, 256, 0, stream>>>(xcat2, x8, csr_pair, rowstart);
    k_conv_mfma<256, 256, 2, 2><<<dim3(mfma_blk, 2), 256, 0, stream>>>(xcat2, w3T, brel3, nullptr, batch, bstart, gfacc, nullptr);

    // head
    k_headpre<<<(NBATCH * 272 + 255) / 256, 256, 0, stream>>>(gfacc, bstart, demog, dw, db, h0);
    k_head_lin<272, 128><<<(NBATCH + 15) / 16, 128, 0, stream>>>(h0, l1w, l1b, h1, NBATCH);
    k_head_bn<<<1, 128, 0, stream>>>(h1, bn1g, bn1b, NBATCH, 128);
    k_head_lin<128, 64><<<(NBATCH + 15) / 16, 64, 0, stream>>>(h1, l2w, l2b, h2, NBATCH);
    k_head_bn<<<1, 64, 0, stream>>>(h2, bn2g, bn2b, NBATCH, 64);
    k_head_out<<<1, 256, 0, stream>>>(h2, l3w, l3b, out);
}

// Round 19
// 616.021 us; speedup vs baseline: 1.0151x; 1.0151x over previous
//
#include <hip/hip_runtime.h>

// Problem constants (from reference)
#define NN 100000      // nodes
#define NE 1600000     // edges
#define NBATCH 100     // graphs
#define NBUCK 391      // ceil(NN / 256) coarse buckets for CSR build
constexpr float EPS = 1e-5f;

typedef unsigned short ushort_t;
typedef unsigned int uint_t;
typedef unsigned char uchar_t;

using short8 = __attribute__((ext_vector_type(8))) short;   // 8 bf16 (4 VGPRs)
using floatx4 = __attribute__((ext_vector_type(4))) float;  // 4 fp32 acc
using floatx2 = __attribute__((ext_vector_type(2))) float;

__device__ __forceinline__ float lrelu(float x) { return x > 0.f ? x : 0.01f * x; }

__device__ __forceinline__ float b2f(ushort_t u) {
    union { uint_t i; float f; } c; c.i = ((uint_t)u) << 16; return c.f;
}
__device__ __forceinline__ ushort_t f2b(float f) {
    union { float f; uint_t i; } c; c.f = f;
    uint_t u = c.i;
    return (ushort_t)((u + 0x7FFFu + ((u >> 16) & 1u)) >> 16);   // RNE
}
__device__ __forceinline__ void unpack8(const uint4 u, float* f) {
    f[0] = b2f(u.x & 0xffff); f[1] = b2f(u.x >> 16);
    f[2] = b2f(u.y & 0xffff); f[3] = b2f(u.y >> 16);
    f[4] = b2f(u.z & 0xffff); f[5] = b2f(u.z >> 16);
    f[6] = b2f(u.w & 0xffff); f[7] = b2f(u.w >> 16);
}
__device__ __forceinline__ void unpack8_f8(const uint2 u, float* f) {
    floatx2 a = __builtin_amdgcn_cvt_pk_f32_fp8(u.x, false);
    floatx2 b = __builtin_amdgcn_cvt_pk_f32_fp8(u.x, true);
    floatx2 c = __builtin_amdgcn_cvt_pk_f32_fp8(u.y, false);
    floatx2 d = __builtin_amdgcn_cvt_pk_f32_fp8(u.y, true);
    f[0] = a[0]; f[1] = a[1]; f[2] = b[0]; f[3] = b[1];
    f[4] = c[0]; f[5] = c[1]; f[6] = d[0]; f[7] = d[1];
}

// ---------------- bucketed CSR build ----------------

__global__ __launch_bounds__(256) void k_bcount(const int* __restrict__ dst,
                                                int* __restrict__ bcnt) {
    __shared__ int h[NBUCK];
    for (int i = threadIdx.x; i < NBUCK; i += 256) h[i] = 0;
    __syncthreads();
    for (int e = blockIdx.x * 256 + threadIdx.x; e < NE; e += gridDim.x * 256)
        atomicAdd(&h[dst[e] >> 8], 1);
    __syncthreads();
    for (int i = threadIdx.x; i < NBUCK; i += 256)
        if (h[i]) atomicAdd(&bcnt[i], h[i]);
}

// scan bucket totals + batch boundaries (batch sorted), 1 block
__global__ __launch_bounds__(512) void k_bscan(const int* __restrict__ bcnt,
                                               int* __restrict__ bbase,
                                               int* __restrict__ bcur,
                                               int* __restrict__ rowstart,
                                               const int* __restrict__ batch,
                                               int* __restrict__ bstart) {
    __shared__ int s[512];
    const int t = threadIdx.x;
    const int v = (t < NBUCK) ? bcnt[t] : 0;
    s[t] = v;
    __syncthreads();
    for (int off = 1; off < 512; off <<= 1) {
        int o = (t >= off) ? s[t - off] : 0;
        __syncthreads();
        s[t] += o;
        __syncthreads();
    }
    const int excl = s[t] - v;
    if (t < NBUCK) { bbase[t] = excl; bcur[t] = excl; }
    if (t == 0) { bbase[NBUCK] = NE; rowstart[NN] = NE; }
    if (t <= NBATCH) {
        int lo = 0, hi = NN;
        while (lo < hi) {
            int mid = (lo + hi) >> 1;
            if (batch[mid] < t) lo = mid + 1; else hi = mid;
        }
        bstart[t] = lo;
    }
}

__global__ __launch_bounds__(256) void k_bscatter(const int* __restrict__ dst,
                                                  const int* __restrict__ srcv,
                                                  const float* __restrict__ ew,
                                                  int* __restrict__ bcur,
                                                  int2* __restrict__ ebuf) {
    __shared__ int h[NBUCK];
    __shared__ int lcur[NBUCK];
    const int chunk = (NE + gridDim.x - 1) / gridDim.x;
    const int beg = blockIdx.x * chunk;
    const int end = (beg + chunk < NE) ? beg + chunk : NE;
    for (int i = threadIdx.x; i < NBUCK; i += 256) h[i] = 0;
    __syncthreads();
    for (int e = beg + threadIdx.x; e < end; e += 256)
        atomicAdd(&h[dst[e] >> 8], 1);
    __syncthreads();
    for (int i = threadIdx.x; i < NBUCK; i += 256)
        lcur[i] = h[i] ? atomicAdd(&bcur[i], h[i]) : 0;
    __syncthreads();
    for (int e = beg + threadIdx.x; e < end; e += 256) {
        const int d = dst[e];
        const int pos = atomicAdd(&lcur[d >> 8], 1);
        ebuf[pos] = make_int2(srcv[e] | ((d & 255) << 20), __float_as_int(ew[e]));
    }
}

__global__ __launch_bounds__(256) void k_bfinal(const int2* __restrict__ ebuf,
                                                const int* __restrict__ bbase,
                                                int* __restrict__ rowstart,
                                                int2* __restrict__ csr_pair) {
    __shared__ int h[256];
    __shared__ int cur[256];
    const int b = blockIdx.x;
    const int t = threadIdx.x;
    const int base = bbase[b];
    const int cnt = bbase[b + 1] - base;
    h[t] = 0;
    __syncthreads();
    for (int i = t; i < cnt; i += 256)
        atomicAdd(&h[(ebuf[base + i].x >> 20) & 255], 1);
    __syncthreads();
    const int v = h[t];
    cur[t] = v;
    __syncthreads();
    for (int off = 1; off < 256; off <<= 1) {
        int o = (t >= off) ? cur[t - off] : 0;
        __syncthreads();
        cur[t] += o;
        __syncthreads();
    }
    const int excl = cur[t] - v;
    const int n = (b << 8) + t;
    if (n < NN) rowstart[n] = base + excl;
    __syncthreads();
    cur[t] = excl;
    __syncthreads();
    for (int i = t; i < cnt; i += 256) {
        const int2 p = ebuf[base + i];
        const int loc = (p.x >> 20) & 255;
        const int pos = base + atomicAdd(&cur[loc], 1);
        csr_pair[pos] = make_int2(p.x & 0xFFFFF, p.y);
    }
}

// ---------------- weight pack: fragment-major, all three convs in one launch -----------------

__device__ __forceinline__ void packone(int idx, const float* __restrict__ wrel,
                                        const float* __restrict__ wroot,
                                        ushort_t* __restrict__ wf, int K, int K2, int DOUT) {
    const int col = idx / K2, k = idx - col * K2;
    const float v = (k < K) ? wrel[k * DOUT + col] : wroot[(k - K) * DOUT + col];
    const int ct = col >> 4, m = col & 15;
    const int kb = k >> 5, q = (k >> 3) & 3, j = k & 7;
    const int lane = m + (q << 4);
    wf[(((size_t)(ct * (K2 / 32) + kb) * 64 + lane) << 3) + j] = f2b(v);
}

__global__ void k_wpackall(const float* __restrict__ wr1, const float* __restrict__ wo1,
                           const float* __restrict__ wr2, const float* __restrict__ wo2,
                           const float* __restrict__ wr3, const float* __restrict__ wo3,
                           ushort_t* __restrict__ w1T, ushort_t* __restrict__ w2T,
                           ushort_t* __restrict__ w3T) {
    int idx = blockIdx.x * 256 + threadIdx.x;
    if (idx < 2048)              packone(idx, wr1, wo1, w1T, 16, 32, 64);
    else if (idx < 18432)        packone(idx - 2048, wr2, wo2, w2T, 64, 128, 128);
    else if (idx < 83968)        packone(idx - 18432, wr3, wo3, w3T, 128, 256, 256);
}

// ---------------- embedding gather -> bf16 x-half of xcat0 ----------------------------------

__global__ void k_gather_b(const int* __restrict__ xi, const float* __restrict__ emb,
                           ushort_t* __restrict__ xcat0) {
    int n = blockIdx.x * blockDim.x + threadIdx.x;
    if (n >= NN) return;
    const float* e = emb + ((size_t)xi[n] << 4);
    uint_t u[8];
#pragma unroll
    for (int j = 0; j < 8; ++j)
        u[j] = (uint_t)f2b(e[2 * j]) | ((uint_t)f2b(e[2 * j + 1]) << 16);
    uint4* o = (uint4*)(xcat0 + (size_t)n * 32 + 16);
    o[0] = {u[0], u[1], u[2], u[3]};
    o[1] = {u[4], u[5], u[6], u[7]};
}

// ---------------- aggregate (bf16 in/out) for conv1 ------------------------------------------

template <int D>
__global__ void k_aggregate_b(ushort_t* __restrict__ xcat, const int2* __restrict__ csr_pair,
                              const int* __restrict__ rowstart) {
    constexpr int LPN = D / 8;
    constexpr int EP = 64 / LPN;
    const int n = blockIdx.x * 4 + (threadIdx.x >> 6);
    const int lane = threadIdx.x & 63;
    const int sl = lane % LPN;
    const int eg = lane / LPN;
    if (n >= NN) return;
    const int beg = rowstart[n], end = rowstart[n + 1];
    float a0[8] = {}, a1[8] = {};
    int i = beg + eg;
    for (; i + EP < end; i += 2 * EP) {
        const int2 p0 = csr_pair[i];
        const int2 p1 = csr_pair[i + EP];
        const float w0 = __int_as_float(p0.y);
        const float w1 = __int_as_float(p1.y);
        const uint4 u0 = *(const uint4*)(xcat + (size_t)p0.x * (2 * D) + D + sl * 8);
        const uint4 u1 = *(const uint4*)(xcat + (size_t)p1.x * (2 * D) + D + sl * 8);
        float f0[8], f1[8];
        unpack8(u0, f0); unpack8(u1, f1);
#pragma unroll
        for (int j = 0; j < 8; ++j) { a0[j] += f0[j] * w0; a1[j] += f1[j] * w1; }
    }
    if (i < end) {
        const int2 p0 = csr_pair[i];
        const float w0 = __int_as_float(p0.y);
        const uint4 u0 = *(const uint4*)(xcat + (size_t)p0.x * (2 * D) + D + sl * 8);
        float f0[8];
        unpack8(u0, f0);
#pragma unroll
        for (int j = 0; j < 8; ++j) a0[j] += f0[j] * w0;
    }
#pragma unroll
    for (int j = 0; j < 8; ++j) a0[j] += a1[j];
#pragma unroll
    for (int m = LPN; m < 64; m <<= 1)
#pragma unroll
        for (int j = 0; j < 8; ++j) a0[j] += __shfl_xor(a0[j], m);
    if (eg == 0) {
        uint_t u[4];
#pragma unroll
        for (int j = 0; j < 4; ++j)
            u[j] = (uint_t)f2b(a0[2 * j]) | ((uint_t)f2b(a0[2 * j + 1]) << 16);
        *(uint4*)(xcat + (size_t)n * (2 * D) + sl * 8) = {u[0], u[1], u[2], u[3]};
    }
}

// ---------------- aggregate: fp8 x reads, bf16 agg writes (conv2: D=64, conv3: D=128) --------
// 2x unroll — measured optimum (4x regressed: VGPR 28->36, occ 66->59%, r18).

template <int D>
__global__ void k_aggregate_f8(ushort_t* __restrict__ xcat, const uchar_t* __restrict__ x8,
                               const int2* __restrict__ csr_pair, const int* __restrict__ rowstart) {
    constexpr int LPN = D / 8;           // lanes per row (8 fp8 each)
    constexpr int EP = 64 / LPN;
    const int n = blockIdx.x * 4 + (threadIdx.x >> 6);
    const int lane = threadIdx.x & 63;
    const int sl = lane % LPN;
    const int eg = lane / LPN;
    if (n >= NN) return;
    const int beg = rowstart[n], end = rowstart[n + 1];
    float a0[8] = {}, a1[8] = {};
    int i = beg + eg;
    for (; i + EP < end; i += 2 * EP) {
        const int2 p0 = csr_pair[i];
        const int2 p1 = csr_pair[i + EP];
        const float w0 = __int_as_float(p0.y);
        const float w1 = __int_as_float(p1.y);
        const uint2 u0 = *(const uint2*)(x8 + (size_t)p0.x * D + sl * 8);
        const uint2 u1 = *(const uint2*)(x8 + (size_t)p1.x * D + sl * 8);
        float f0[8], f1[8];
        unpack8_f8(u0, f0); unpack8_f8(u1, f1);
#pragma unroll
        for (int j = 0; j < 8; ++j) { a0[j] += f0[j] * w0; a1[j] += f1[j] * w1; }
    }
    if (i < end) {
        const int2 p0 = csr_pair[i];
        const float w0 = __int_as_float(p0.y);
        const uint2 u0 = *(const uint2*)(x8 + (size_t)p0.x * D + sl * 8);
        float f0[8];
        unpack8_f8(u0, f0);
#pragma unroll
        for (int j = 0; j < 8; ++j) a0[j] += f0[j] * w0;
    }
#pragma unroll
    for (int j = 0; j < 8; ++j) a0[j] += a1[j];
#pragma unroll
    for (int m = LPN; m < 64; m <<= 1)
#pragma unroll
        for (int j = 0; j < 8; ++j) a0[j] += __shfl_xor(a0[j], m);
    if (eg == 0) {
        uint_t u[4];
#pragma unroll
        for (int j = 0; j < 4; ++j)
            u[j] = (uint_t)f2b(a0[2 * j]) | ((uint_t)f2b(a0[2 * j + 1]) << 16);
        *(uint4*)(xcat + (size_t)n * (2 * D) + sl * 8) = {u[0], u[1], u[2], u[3]};
    }
}

// ---------------- conv GEMM via bf16 MFMA (fragment-major B) --------------------------------
// MODE 1: fp32 out + per-(batch,col) sum/sumsq stats. MODE 2: gf fusion (split-K via blockIdx.y).

template <int K2, int DOUT, int MODE, int NSPLIT>
__global__ __launch_bounds__(256) void k_conv_mfma(
        const ushort_t* __restrict__ xcat, const ushort_t* __restrict__ wfrag,
        const float* __restrict__ brel, float* __restrict__ outp,
        const int* __restrict__ batch, const int* __restrict__ bstart,
        float* __restrict__ sacc, float* __restrict__ qacc) {
    constexpr int CW = DOUT / 64;
    constexpr int KBTOT = K2 / 32;
    constexpr int KSTEPS = KBTOT / NSPLIT;
    const int lane = threadIdx.x & 63;
    const int wv = threadIdx.x >> 6;
    const int m = lane & 15;
    const int quad = lane >> 4;
    const int r0 = blockIdx.x * 64;
    const int kb0 = blockIdx.y * KSTEPS;

    floatx4 acc[4][CW] = {};

    const ushort_t* arow[4];
#pragma unroll
    for (int r = 0; r < 4; ++r) {
        int an = r0 + r * 16 + m; if (an >= NN) an = NN - 1;
        arow[r] = xcat + (size_t)an * K2 + quad * 8 + kb0 * 32;
    }
    const ushort_t* bfr[CW];
#pragma unroll
    for (int c = 0; c < CW; ++c)
        bfr[c] = wfrag + (((size_t)((wv * CW + c) * KBTOT + kb0) * 64 + lane) << 3);

#pragma unroll
    for (int s = 0; s < KSTEPS; ++s) {
        short8 a[4], b[CW];
#pragma unroll
        for (int r = 0; r < 4; ++r) a[r] = *(const short8*)(arow[r] + s * 32);
#pragma unroll
        for (int c = 0; c < CW; ++c) b[c] = *(const short8*)(bfr[c] + (size_t)s * 512);
#pragma unroll
        for (int r = 0; r < 4; ++r)
#pragma unroll
            for (int c = 0; c < CW; ++c)
                acc[r][c] = __builtin_amdgcn_mfma_f32_16x16x32_bf16(a[r], b[c], acc[r][c], 0, 0, 0);
    }

    float bias[CW];
#pragma unroll
    for (int c = 0; c < CW; ++c)
        bias[c] = (NSPLIT == 1 || blockIdx.y == 0) ? brel[(wv * CW + c) * 16 + m] : 0.f;

    if constexpr (MODE == 1) {
#pragma unroll
        for (int c = 0; c < CW; ++c) {
            const int col = (wv * CW + c) * 16 + m;
#pragma unroll
            for (int r = 0; r < 4; ++r)
#pragma unroll
                for (int rr = 0; rr < 4; ++rr) {
                    const int row = r0 + r * 16 + quad * 4 + rr;
                    if (row < NN)
                        outp[(size_t)row * DOUT + col] = acc[r][c][rr] + bias[c];
                }
        }
        const int rtop = (r0 + 63 < NN) ? r0 + 63 : NN - 1;
        const int sb0 = batch[r0];
        const int sb1 = batch[rtop];
        for (int sb = sb0; sb <= sb1; ++sb) {
            const int lo = (bstart[sb] > r0) ? bstart[sb] : r0;
            int hi = bstart[sb + 1];
            if (hi > r0 + 64) hi = r0 + 64;
            float s[CW], q[CW];
#pragma unroll
            for (int c = 0; c < CW; ++c) { s[c] = 0.f; q[c] = 0.f; }
#pragma unroll
            for (int r = 0; r < 4; ++r)
#pragma unroll
                for (int rr = 0; rr < 4; ++rr) {
                    const int row = r0 + r * 16 + quad * 4 + rr;
                    if (row >= lo && row < hi) {
#pragma unroll
                        for (int c = 0; c < CW; ++c) {
                            const float v = acc[r][c][rr] + bias[c];
                            s[c] += v; q[c] += v * v;
                        }
                    }
                }
#pragma unroll
            for (int c = 0; c < CW; ++c) {
                s[c] += __shfl_xor(s[c], 16); s[c] += __shfl_xor(s[c], 32);
                q[c] += __shfl_xor(q[c], 16); q[c] += __shfl_xor(q[c], 32);
            }
            if (quad == 0) {
#pragma unroll
                for (int c = 0; c < CW; ++c) {
                    const int col = (wv * CW + c) * 16 + m;
                    atomicAdd(&sacc[sb * DOUT + col], s[c]);
                    atomicAdd(&qacc[sb * DOUT + col], q[c]);
                }
            }
        }
    } else {
        const int rtop = (r0 + 63 < NN) ? r0 + 63 : NN - 1;
        const int sb0 = batch[r0];
        const int sb1 = batch[rtop];
        for (int sb = sb0; sb <= sb1; ++sb) {
            const int lo = (bstart[sb] > r0) ? bstart[sb] : r0;
            int hi = bstart[sb + 1];
            if (hi > r0 + 64) hi = r0 + 64;
            float s[CW];
#pragma unroll
            for (int c = 0; c < CW; ++c) s[c] = 0.f;
#pragma unroll
            for (int r = 0; r < 4; ++r)
#pragma unroll
                for (int rr = 0; rr < 4; ++rr) {
                    const int row = r0 + r * 16 + quad * 4 + rr;
                    if (row >= lo && row < hi) {
#pragma unroll
                        for (int c = 0; c < CW; ++c) s[c] += acc[r][c][rr] + bias[c];
                    }
                }
#pragma unroll
            for (int c = 0; c < CW; ++c) {
                s[c] += __shfl_xor(s[c], 16);
                s[c] += __shfl_xor(s[c], 32);
            }
            if (quad == 0) {
#pragma unroll
                for (int c = 0; c < CW; ++c)
                    atomicAdd(&sacc[sb * 256 + (wv * CW + c) * 16 + m], s[c]);
            }
        }
    }
}

// graph features + demographics -> h0 (fused)
__global__ void k_headpre(const float* __restrict__ gfacc, const int* __restrict__ bstart,
                          const float* __restrict__ dg, const float* __restrict__ dw,
                          const float* __restrict__ db, float* __restrict__ h0) {
    int idx = blockIdx.x * blockDim.x + threadIdx.x;
    if (idx >= NBATCH * 272) return;
    int b = idx / 272, c = idx - b * 272;
    if (c < 256) {
        float cnt = fmaxf((float)(bstart[b + 1] - bstart[b]), 1.f);
        h0[idx] = gfacc[b * 256 + c] / cnt;
    } else {
        int j = c - 256;
        float acc = db[j];
        for (int k = 0; k < 4; ++k) acc += dg[b * 4 + k] * dw[k * 16 + j];
        h0[idx] = acc;
    }
}

// ---------------- graph-norm apply (1 pass) --------------------------------------------------

template <int D, int OST, bool F8>
__global__ __launch_bounds__(256) void k_gnapply(
        const float* __restrict__ xf, ushort_t* __restrict__ xout, uchar_t* __restrict__ x8out,
        const int* __restrict__ bstart, const float* __restrict__ sacc,
        const float* __restrict__ qacc, const float* __restrict__ a,
        const float* __restrict__ g, const float* __restrict__ bb) {
    const int b = blockIdx.x;
    const int col0 = blockIdx.y * 64;
    const int c4 = (threadIdx.x & 15) * 4;
    const int rg = threadIdx.x >> 4;
    const int beg = bstart[b], end = bstart[b + 1];
    const float cntf = fmaxf((float)(end - beg), 1.f);

    const float4 S = *(const float4*)&sacc[b * D + col0 + c4];
    const float4 Q = *(const float4*)&qacc[b * D + col0 + c4];
    const float4 al4 = *(const float4*)&a[col0 + c4];
    const float4 g4 = *(const float4*)&g[col0 + c4];
    const float4 bb4 = *(const float4*)&bb[col0 + c4];
    float mean[4], inv[4];
    const float Sv[4] = {S.x, S.y, S.z, S.w};
    const float Qv[4] = {Q.x, Q.y, Q.z, Q.w};
    const float av[4] = {al4.x, al4.y, al4.z, al4.w};
#pragma unroll
    for (int c = 0; c < 4; ++c) {
        const float mm = Sv[c] / cntf;
        const float ex2 = Qv[c] / cntf;
        const float var = fmaxf(ex2 - mm * mm * (2.f * av[c] - av[c] * av[c]), 0.f);
        mean[c] = mm;
        inv[c] = 1.f / sqrtf(var + EPS);
    }
    for (int r = beg + rg; r < end; r += 16) {
        const float4 v = *(const float4*)&xf[(size_t)r * D + col0 + c4];
        const float y0 = lrelu(g4.x * (v.x - av[0] * mean[0]) * inv[0] + bb4.x);
        const float y1 = lrelu(g4.y * (v.y - av[1] * mean[1]) * inv[1] + bb4.y);
        const float y2 = lrelu(g4.z * (v.z - av[2] * mean[2]) * inv[2] + bb4.z);
        const float y3 = lrelu(g4.w * (v.w - av[3] * mean[3]) * inv[3] + bb4.w);
        uint2 o;
        o.x = (uint_t)f2b(y0) | ((uint_t)f2b(y1) << 16);
        o.y = (uint_t)f2b(y2) | ((uint_t)f2b(y3) << 16);
        *(uint2*)&xout[(size_t)r * OST + col0 + c4] = o;
        if constexpr (F8) {
            uint_t p = __builtin_amdgcn_cvt_pk_fp8_f32(y0, y1, 0, false);
            p = __builtin_amdgcn_cvt_pk_fp8_f32(y2, y3, p, true);
            *(uint_t*)&x8out[(size_t)r * D + col0 + c4] = p;
        }
    }
}

// ---------------- head ----------------------------------------------------------------------

template <int K, int C>
__global__ __launch_bounds__(C) void k_head_lin(const float* __restrict__ in,
                                                const float* __restrict__ w,
                                                const float* __restrict__ bias,
                                                float* __restrict__ z, int rows) {
    __shared__ float s_in[16][K];
    const int j = threadIdx.x;
    const int r0 = blockIdx.x * 16;
    for (int idx = threadIdx.x; idx < 16 * K; idx += C) {
        int r = idx / K, k = idx - r * K;
        s_in[r][k] = (r0 + r < rows) ? in[(size_t)(r0 + r) * K + k] : 0.f;
    }
    __syncthreads();
    float acc[16];
#pragma unroll
    for (int r = 0; r < 16; ++r) acc[r] = 0.f;
    for (int k = 0; k < K; ++k) {
        const float wv = w[k * C + j];
#pragma unroll
        for (int r = 0; r < 16; ++r) acc[r] += s_in[r][k] * wv;
    }
    const float bj = bias[j];
#pragma unroll
    for (int r = 0; r < 16; ++r)
        if (r0 + r < rows) z[(size_t)(r0 + r) * C + j] = acc[r] + bj;
}

__global__ void k_head_bn(float* __restrict__ z, const float* __restrict__ g,
                          const float* __restrict__ b, int rows, int C) {
    const int j = threadIdx.x;
    if (j >= C) return;
    float s = 0.f, q = 0.f;
    for (int i = 0; i < rows; ++i) { const float v = z[i * C + j]; s += v; q += v * v; }
    const float m = s / rows;
    const float var = fmaxf(q / rows - m * m, 0.f);
    const float inv = 1.f / sqrtf(var + EPS);
    const float gg = g[j], bb = b[j];
    for (int i = 0; i < rows; ++i)
        z[i * C + j] = lrelu(gg * (z[i * C + j] - m) * inv + bb);
}

__global__ __launch_bounds__(256) void k_head_out(const float* __restrict__ h2,
                                                  const float* __restrict__ w,
                                                  const float* __restrict__ b,
                                                  float* __restrict__ out) {
    __shared__ float s[NBATCH * 65];
    for (int idx = threadIdx.x; idx < NBATCH * 64; idx += 256) {
        int i = idx >> 6, k = idx & 63;
        s[i * 65 + k] = h2[idx];
    }
    __syncthreads();
    const int i = threadIdx.x;
    if (i < NBATCH) {
        float a0 = b[0], a1 = b[1], a2 = b[2];
        for (int k = 0; k < 64; ++k) {
            const float v = s[i * 65 + k];
            a0 += v * w[k * 3 + 0];
            a1 += v * w[k * 3 + 1];
            a2 += v * w[k * 3 + 2];
        }
        out[i * 3 + 0] = a0; out[i * 3 + 1] = a1; out[i * 3 + 2] = a2;
    }
}

// ---------------- launcher ----------------

extern "C" void kernel_launch(void* const* d_in, const int* in_sizes, int n_in,
                              void* d_out, int out_size, void* d_ws, size_t ws_size,
                              hipStream_t stream) {
    const int*   x_idx  = (const int*)d_in[0];
    const int*   ei     = (const int*)d_in[1];
    const float* eattr  = (const float*)d_in[2];
    const int*   batch  = (const int*)d_in[3];
    const float* demog  = (const float*)d_in[4];
    const float* emb    = (const float*)d_in[5];
    const float* wrel1  = (const float*)d_in[6];
    const float* brel1  = (const float*)d_in[7];
    const float* wroot1 = (const float*)d_in[8];
    const float* wrel2  = (const float*)d_in[9];
    const float* brel2  = (const float*)d_in[10];
    const float* wroot2 = (const float*)d_in[11];
    const float* wrel3  = (const float*)d_in[12];
    const float* brel3  = (const float*)d_in[13];
    const float* wroot3 = (const float*)d_in[14];
    const float* gn1g = (const float*)d_in[15];
    const float* gn1b = (const float*)d_in[16];
    const float* gn1a = (const float*)d_in[17];
    const float* gn2g = (const float*)d_in[18];
    const float* gn2b = (const float*)d_in[19];
    const float* gn2a = (const float*)d_in[20];
    const float* dw   = (const float*)d_in[21];
    const float* db   = (const float*)d_in[22];
    const float* l1w  = (const float*)d_in[23];
    const float* l1b  = (const float*)d_in[24];
    const float* bn1g = (const float*)d_in[25];
    const float* bn1b = (const float*)d_in[26];
    const float* l2w  = (const float*)d_in[27];
    const float* l2b  = (const float*)d_in[28];
    const float* bn2g = (const float*)d_in[29];
    const float* bn2b = (const float*)d_in[30];
    const float* l3w  = (const float*)d_in[31];
    const float* l3b  = (const float*)d_in[32];
    float* out = (float*)d_out;

    float*    W     = (float*)d_ws;
    float*    xf    = W;                                   // fp32 conv out, 12.8M floats
    int2*     ebuf  = (int2*)W;                            // NE int2 (CSR build only)
    // contiguous zero-init region: gfacc | sacc1 | qacc1 | sacc2 | qacc2 | bcnt
    float*    gfacc = W + 12800000;                        // 25600
    float*    sacc1 = gfacc + 25600;                       // 6400
    float*    qacc1 = sacc1 + 6400;                        // 6400
    float*    sacc2 = qacc1 + 6400;                        // 12800
    float*    qacc2 = sacc2 + 12800;                       // 12800
    int*      bcnt  = (int*)(qacc2 + 12800);               // NBUCK
    ushort_t* xcat0 = (ushort_t*)(W + 25600000);           // NN*32 bf16  [agg0|x0]
    ushort_t* xcat1 = (ushort_t*)(W + 27200000);           // NN*128 bf16 [agg1|x1]
    ushort_t* xcat2 = (ushort_t*)(W + 33600000);           // NN*256 bf16 [agg2|x2]
    ushort_t* w1T   = (ushort_t*)(W + 46400000);           // 2048
    ushort_t* w2T   = w1T + 2048;                          // 16384
    ushort_t* w3T   = w2T + 16384;                         // 65536
    int2*     csr_pair = (int2*)(W + 46450000);            // NE int2
    int*      rowstart = (int*)(W + 49650000);             // NN+1
    int*      bstart   = (int*)(W + 49760000);             // NBATCH+1
    int*      bbase    = (int*)(W + 49762000);             // NBUCK+1
    int*      bcur     = (int*)(W + 49763000);             // NBUCK
    float*    h0 = W + 49770000;                           // 100*272
    float*    h1 = h0 + 27200;
    float*    h2 = h1 + 12800;
    uchar_t*  x8_2 = (uchar_t*)(W + 49860000);             // NN*128 fp8 (x2 copy)
    uchar_t*  x8_1 = (uchar_t*)(W + 53060000);             // NN*64 fp8 (x1 copy)

    const int* src = ei;
    const int* dst = ei + NE;

    const int mfma_blk = (NN + 63) / 64;     // 1563 (64 rows/block)
    const int nagg_blk = (NN + 3) / 4;       // 1 node/wave, 4 waves/block

    // single memset for all accumulators + bcnt (contiguous)
    hipMemsetAsync(gfacc, 0, (25600 + 6400 + 6400 + 12800 + 12800) * sizeof(float)
                             + NBUCK * sizeof(int), stream);

    // ---- bucketed CSR build (by dst) + batch bounds ----
    k_bcount<<<256, 256, 0, stream>>>(dst, bcnt);
    k_bscan<<<1, 512, 0, stream>>>(bcnt, bbase, bcur, rowstart, batch, bstart);
    k_bscatter<<<256, 256, 0, stream>>>(dst, src, eattr, bcur, ebuf);
    k_bfinal<<<NBUCK, 256, 0, stream>>>(ebuf, bbase, rowstart, csr_pair);

    k_wpackall<<<(83968 + 255) / 256, 256, 0, stream>>>(wrel1, wroot1, wrel2, wroot2,
                                                        wrel3, wroot3, w1T, w2T, w3T);

    // x0 (bf16) into xcat0 x-half
    k_gather_b<<<(NN + 255) / 256, 256, 0, stream>>>(x_idx, emb, xcat0);

    // conv1: [agg0|x0](K2=32) @ w1T -> xf (fp32 NN x 64) + graphnorm stats
    k_aggregate_b<16><<<nagg_blk, 256, 0, stream>>>(xcat0, csr_pair, rowstart);
    k_conv_mfma<32, 64, 1, 1><<<mfma_blk, 256, 0, stream>>>(xcat0, w1T, brel1, xf, batch, bstart, sacc1, qacc1);
    k_gnapply<64, 128, true><<<dim3(NBATCH, 1), 256, 0, stream>>>(xf, xcat1 + 64, x8_1,
                                                                  bstart, sacc1, qacc1, gn1a, gn1g, gn1b);

    // conv2: agg from fp8 x1; [agg1|x1](K2=128) @ w2T -> xf + stats; apply writes bf16 + fp8
    k_aggregate_f8<64><<<nagg_blk, 256, 0, stream>>>(xcat1, x8_1, csr_pair, rowstart);
    k_conv_mfma<128, 128, 1, 1><<<mfma_blk, 256, 0, stream>>>(xcat1, w2T, brel2, xf, batch, bstart, sacc2, qacc2);
    k_gnapply<128, 256, true><<<dim3(NBATCH, 2), 256, 0, stream>>>(xf, xcat2 + 128, x8_2,
                                                                   bstart, sacc2, qacc2, gn2a, gn2g, gn2b);

    // conv3: agg from fp8 x2; [agg2|x2](K2=256) @ w3T -> gfacc (split-K=2)
    k_aggregate_f8<128><<<nagg_blk, 256, 0, stream>>>(xcat2, x8_2, csr_pair, rowstart);
    k_conv_mfma<256, 256, 2, 2><<<dim3(mfma_blk, 2), 256, 0, stream>>>(xcat2, w3T, brel3, nullptr, batch, bstart, gfacc, nullptr);

    // head
    k_headpre<<<(NBATCH * 272 + 255) / 256, 256, 0, stream>>>(gfacc, bstart, demog, dw, db, h0);
    k_head_lin<272, 128><<<(NBATCH + 15) / 16, 128, 0, stream>>>(h0, l1w, l1b, h1, NBATCH);
    k_head_bn<<<1, 128, 0, stream>>>(h1, bn1g, bn1b, NBATCH, 128);
    k_head_lin<128, 64><<<(NBATCH + 15) / 16, 64, 0, stream>>>(h1, l2w, l2b, h2, NBATCH);
    k_head_bn<<<1, 64, 0, stream>>>(h2, bn2g, bn2b, NBATCH, 64);
    k_head_out<<<1, 256, 0, stream>>>(h2, l3w, l3b, out);
}